// Round 8
// baseline (112.614 us; speedup 1.0000x reference)
//
#include <hip/hip_runtime.h>
#include <hip/hip_bf16.h>
#include <stdint.h>

#define BATCH 2
#define NPTS  2048
#define CIN   64
#define COUT  64
#define NCELL 9

// knorm = 315 / (64*pi*0.1^9) -- folded into dC at prep
#define KNORM 1.5666851e9f
#define R2 0.01f

typedef __attribute__((ext_vector_type(8))) __bf16 bf16x8;
typedef __attribute__((ext_vector_type(4))) float  f32x4;

union B8 { uint4 u; bf16x8 v; };

static __device__ __forceinline__ unsigned pk2(float a, float b) {
    union { __hip_bfloat162 h; unsigned u; } cv;
    cv.h = __float22bfloat162_rn(make_float2(a, b));
    return cv.u;
}

// ---------------------------------------------------------------------------
// Workspace:
//   posT  float2[B*N]                    32 KB
//   dC    bf16  [B][C][N]  (c-major)    512 KB  (L2-resident; KNORM folded in)
//   WB    bf16  [9][2ks][4ob][64][8]     72 KB  -- GEMM2 B pre-swizzled frags
// ---------------------------------------------------------------------------

__global__ __launch_bounds__(256) void prep_kernel(
    const float* __restrict__ locs, const float* __restrict__ data,
    const float* __restrict__ density, const float* __restrict__ weight,
    const float* __restrict__ bias,
    float2* __restrict__ posT, uint16_t* __restrict__ dC,
    uint16_t* __restrict__ WB, float* __restrict__ out)
{
    const int tid = threadIdx.x;
    const int g = blockIdx.x;
    if (g < 256) {
        // dC[b][c][j] = bf16( KNORM * data / (invmass * density) )
        int e = g * 256 + tid;             // 4 j each
        int j4 = e & 511, bc = e >> 9;
        int b = bc >> 6;
        float4 dv = *(const float4*)(data + bc * 2048 + j4 * 4);
        float4 de = *(const float4*)(density + b * 2048 + j4 * 4);
        int jb = (b * 2048 + j4 * 4) * 3 + 2;
        float m0 = locs[jb], m1 = locs[jb + 3], m2 = locs[jb + 6], m3 = locs[jb + 9];
        float v0 = KNORM * dv.x / (m0 * de.x);
        float v1 = KNORM * dv.y / (m1 * de.y);
        float v2 = KNORM * dv.z / (m2 * de.z);
        float v3 = KNORM * dv.w / (m3 * de.w);
        *(uint2*)(dC + bc * 2048 + j4 * 4) = make_uint2(pk2(v0, v1), pk2(v2, v3));
    } else if (g < 272) {
        int jj = (g - 256) * 256 + tid;
        posT[jj] = make_float2(locs[jj * 3], locs[jj * 3 + 1]);
    } else if (g < 272 + NCELL) {
        // WB[cell][ks][ob][lane][jj]: o = ob*16 + (lane&15), c = ks*32 + quad*8 + jj
        int cell = g - 272;
        for (int it = 0; it < 16; it++) {
            int e = it * 256 + tid;
            int ks = e >> 11, ob = (e >> 9) & 3, lane = (e >> 3) & 63, jj = e & 7;
            int o = ob * 16 + (lane & 15);
            int c = ks * 32 + ((lane >> 4) & 3) * 8 + jj;
            union { __hip_bfloat16 h; uint16_t u; } cv;
            cv.h = __float2bfloat16(weight[(o * 64 + c) * 9 + cell]);
            WB[cell * 4096 + e] = cv.u;
        }
    } else {
        // out[b][o][i] = bias[o]  (atomic accumulation target)
        const int gb = g - (272 + NCELL);
#pragma unroll
        for (int r = 0; r < 2; r++) {
            int e4 = (gb * 512 + r * 256 + tid) * 4;
            float bv = bias[(e4 >> 11) & 63];
            *(float4*)(out + e4) = make_float4(bv, bv, bv, bv);
        }
    }
}

// ---------------------------------------------------------------------------
// Fused conv: block = 16-i tile x 512-j quarter (16 chunks of 32 j), 4 waves.
// Cells split 3/2/2/2 over waves (acc[3][4] = 48 VGPR, no spill); every wave
// walks all 16 chunks; B-frags (dcoef) read directly from L2/L1-hot dC with
// 1-deep register prefetch -- NO LDS staging, NO barriers in the K-loop.
// GEMM2 per-wave (private LDS slice), one barrier, 4-wave reduce, fp32
// atomics into bias-initialized out.
// ---------------------------------------------------------------------------
__global__ __launch_bounds__(256, 3) void conv_kernel(
    const float2* __restrict__ posT, const uint16_t* __restrict__ dC,
    const uint16_t* __restrict__ WB, float* __restrict__ out)
{
    __shared__ float sft[4][16 * 68];

    const int tid  = threadIdx.x;
    const int lane = tid & 63;
    const int wid  = tid >> 6;
    const int cl   = lane & 15;
    const int quad = lane >> 4;
    const int bx   = blockIdx.x;
    const int b    = bx >> 9;
    const int i0   = ((bx >> 2) & 127) * 16;
    const int jb0  = (bx & 3) * 512;          // j-quarter base

    // cells per wave: wid0:{0,1,2} wid1:{3,4} wid2:{5,6} wid3:{7,8}
    const int c0 = (wid == 0) ? 0 : (1 + wid * 2);
    const int nc = (wid == 0) ? 3 : 2;
    float oxr[3], oyr[3];
#pragma unroll
    for (int ci = 0; ci < 3; ci++) {
        int k = c0 + (ci < nc ? ci : 0);
        oxr[ci] = (float)(k / 3 - 1) * 0.05f;
        oyr[ci] = (float)(k % 3 - 1) * 0.05f;
    }

    const float2 pI = posT[b * 2048 + i0 + cl];

    f32x4 acc[3][4];
#pragma unroll
    for (int ci = 0; ci < 3; ci++)
#pragma unroll
        for (int nb = 0; nb < 4; nb++) acc[ci][nb] = (f32x4){0.f, 0.f, 0.f, 0.f};

    // B-frag bases: element (c = nb*16 + cl, j = jb0 + t*32 + quad*8 + jj)
    const uint16_t* rb0 = dC + (b * 64 +  0 + cl) * 2048 + jb0 + quad * 8;
    const uint16_t* rb1 = rb0 + 16 * 2048;
    const uint16_t* rb2 = rb0 + 32 * 2048;
    const uint16_t* rb3 = rb0 + 48 * 2048;
    const float2* pjb = posT + b * 2048 + jb0 + quad * 8;

    B8 bfc[4];
    bfc[0].u = *(const uint4*)rb0;
    bfc[1].u = *(const uint4*)rb1;
    bfc[2].u = *(const uint4*)rb2;
    bfc[3].u = *(const uint4*)rb3;

#pragma unroll 2
    for (int t = 0; t < 16; t++) {
        B8 bfn[4];
        if (t < 15) {                          // prefetch next chunk's B-frags
            bfn[0].u = *(const uint4*)(rb0 + (t + 1) * 32);
            bfn[1].u = *(const uint4*)(rb1 + (t + 1) * 32);
            bfn[2].u = *(const uint4*)(rb2 + (t + 1) * 32);
            bfn[3].u = *(const uint4*)(rb3 + (t + 1) * 32);
        }

        // my 8 pair geometries (pos L1-hot: all 4 waves read the same chunk)
        const float4* pp = (const float4*)(pjb + t * 32);
        float4 q0 = pp[0], q1 = pp[1], q2 = pp[2], q3 = pp[3];
        float dyv[8], ru0[8], ru1[8], ru2[8];
        {
            float dxv[8];
            dxv[0] = pI.x - q0.x; dyv[0] = pI.y - q0.y;
            dxv[1] = pI.x - q0.z; dyv[1] = pI.y - q0.w;
            dxv[2] = pI.x - q1.x; dyv[2] = pI.y - q1.y;
            dxv[3] = pI.x - q1.z; dyv[3] = pI.y - q1.w;
            dxv[4] = pI.x - q2.x; dyv[4] = pI.y - q2.y;
            dxv[5] = pI.x - q2.z; dyv[5] = pI.y - q2.w;
            dxv[6] = pI.x - q3.x; dyv[6] = pI.y - q3.y;
            dxv[7] = pI.x - q3.z; dyv[7] = pI.y - q3.w;
#pragma unroll
            for (int p = 0; p < 8; p++) {
                float a0 = dxv[p] - 0.05f;
                float a1 = dxv[p];
                float a2 = dxv[p] + 0.05f;
                ru0[p] = fmaf(-a0, a0, R2);    // R2 - ax^2, shared across cells
                ru1[p] = fmaf(-a1, a1, R2);
                ru2[p] = fmaf(-a2, a2, R2);
            }
        }

#pragma unroll
        for (int ci = 0; ci < 3; ci++) {
            if (ci < nc) {                     // wave-uniform
                int k = c0 + ci;
                const float oy = oyr[ci];
                float w[8];
#pragma unroll
                for (int p = 0; p < 8; p++) {
                    float ru = (k < 3) ? ru0[p] : (k < 6) ? ru1[p] : ru2[p];
                    float cy = dyv[p] + oy;
                    float tt = fmaf(-cy, cy, ru);
                    float mt = fmaxf(tt, 0.0f);
                    w[p] = (mt * mt) * mt;     // knorm folded into dC
                }
                B8 af;
                af.u = make_uint4(pk2(w[0], w[1]), pk2(w[2], w[3]),
                                  pk2(w[4], w[5]), pk2(w[6], w[7]));
#pragma unroll
                for (int nb = 0; nb < 4; nb++)
                    acc[ci][nb] = __builtin_amdgcn_mfma_f32_16x16x32_bf16(
                        af.v, bfc[nb].v, acc[ci][nb], 0, 0, 0);
            }
        }

        if (t < 15) {
            bfc[0] = bfn[0]; bfc[1] = bfn[1];
            bfc[2] = bfn[2]; bfc[3] = bfn[3];
        }
    }

    // ---- GEMM2 per wave: 16i x 64o partial over own cells ------------------
    float* scr = &sft[wid][0];
    f32x4 acc2[4];
#pragma unroll
    for (int ob = 0; ob < 4; ob++) acc2[ob] = (f32x4){0.f, 0.f, 0.f, 0.f};

#pragma unroll
    for (int ci = 0; ci < 3; ci++) {
        if (ci < nc) {
            // C-frag (row=i=quad*4+r, col=c=nb*16+cl) -> scr[i][c]
#pragma unroll
            for (int nb = 0; nb < 4; nb++)
#pragma unroll
                for (int r = 0; r < 4; r++)
                    scr[(quad * 4 + r) * 68 + nb * 16 + cl] = acc[ci][nb][r];
            // A-frags (m=i=cl, k'=c=quad*8+jj); in-wave LDS ordering via lgkmcnt
            int k = c0 + ci;
#pragma unroll
            for (int ks = 0; ks < 2; ks++) {
                const float* fp = &scr[cl * 68 + ks * 32 + quad * 8];
                float4 lo = *(const float4*)fp;
                float4 hi = *(const float4*)(fp + 4);
                B8 af;
                af.u = make_uint4(pk2(lo.x, lo.y), pk2(lo.z, lo.w),
                                  pk2(hi.x, hi.y), pk2(hi.z, hi.w));
#pragma unroll
                for (int ob = 0; ob < 4; ob++) {
                    B8 wf;
                    wf.u = *(const uint4*)(WB + k * 4096 + (ks * 4 + ob) * 512 + lane * 8);
                    acc2[ob] = __builtin_amdgcn_mfma_f32_16x16x32_bf16(
                        af.v, wf.v, acc2[ob], 0, 0, 0);
                }
            }
        }
    }

    // acc2 C-frag (row=i=quad*4+r, col o = ob*16+cl) -> scr[i][o]
#pragma unroll
    for (int ob = 0; ob < 4; ob++)
#pragma unroll
        for (int r = 0; r < 4; r++)
            scr[(quad * 4 + r) * 68 + ob * 16 + cl] = acc2[ob][r];
    __syncthreads();

    // reduce the 4 wave slices; 4 atomics/thread (4-way j-quarter contention)
    {
        const int i  = tid & 15;
        const int og = tid >> 4;               // 16 groups of 4 consecutive o
        float4 s0 = *(const float4*)&sft[0][i * 68 + og * 4];
        float4 s1 = *(const float4*)&sft[1][i * 68 + og * 4];
        float4 s2 = *(const float4*)&sft[2][i * 68 + og * 4];
        float4 s3 = *(const float4*)&sft[3][i * 68 + og * 4];
        float v0 = s0.x + s1.x + s2.x + s3.x;
        float v1 = s0.y + s1.y + s2.y + s3.y;
        float v2 = s0.z + s1.z + s2.z + s3.z;
        float v3 = s0.w + s1.w + s2.w + s3.w;
        float* op = out + (b * 64 + og * 4) * 2048 + i0 + i;
        unsafeAtomicAdd(op + 0 * 2048, v0);
        unsafeAtomicAdd(op + 1 * 2048, v1);
        unsafeAtomicAdd(op + 2 * 2048, v2);
        unsafeAtomicAdd(op + 3 * 2048, v3);
    }
}

extern "C" void kernel_launch(void* const* d_in, const int* in_sizes, int n_in,
                              void* d_out, int out_size, void* d_ws, size_t ws_size,
                              hipStream_t stream)
{
    const float* locs    = (const float*)d_in[0];   // (B, N, 3)
    const float* data    = (const float*)d_in[1];   // (B, CIN, N)
    const float* density = (const float*)d_in[2];   // (B, N)
    const float* weight  = (const float*)d_in[3];   // (COUT, CIN, 9)
    const float* bias    = (const float*)d_in[4];   // (COUT,)
    float* out = (float*)d_out;                     // (B, COUT, N)

    float2*   posT = (float2*)d_ws;                             // 32768 B
    uint16_t* dC   = (uint16_t*)((char*)d_ws + 32768);          // 524288 B
    uint16_t* WB   = (uint16_t*)((char*)d_ws + 32768 + 524288); // 73728 B

    prep_kernel<<<272 + NCELL + 128, 256, 0, stream>>>(
        locs, data, density, weight, bias, posT, dC, WB, out);
    conv_kernel<<<BATCH * 128 * 4, 256, 0, stream>>>(posT, dC, WB, out);
}

// Round 9
// 108.867 us; speedup vs baseline: 1.0344x; 1.0344x over previous
//
#include <hip/hip_runtime.h>
#include <hip/hip_bf16.h>
#include <stdint.h>

#define BATCH 2
#define NPTS  2048
#define CIN   64
#define COUT  64
#define NCELL 9

// knorm = 315 / (64*pi*0.1^9) -- folded into dC at prep
#define KNORM 1.5666851e9f
#define R2 0.01f

typedef __attribute__((ext_vector_type(8))) __bf16 bf16x8;
typedef __attribute__((ext_vector_type(4))) float  f32x4;

union B8 { uint4 u; bf16x8 v; };

static __device__ __forceinline__ unsigned pk2(float a, float b) {
    union { __hip_bfloat162 h; unsigned u; } cv;
    cv.h = __float22bfloat162_rn(make_float2(a, b));
    return cv.u;
}

// ---------------------------------------------------------------------------
// Workspace:
//   posT  float2[B*N]                    32 KB
//   dC    bf16  [B][C][N]  (c-major)    512 KB  (L2-resident; KNORM folded in)
//   WB    bf16  [9][2ks][4ob][64][8]     72 KB  -- GEMM2 B pre-swizzled frags
// ---------------------------------------------------------------------------

__global__ __launch_bounds__(256) void prep_kernel(
    const float* __restrict__ locs, const float* __restrict__ data,
    const float* __restrict__ density, const float* __restrict__ weight,
    const float* __restrict__ bias,
    float2* __restrict__ posT, uint16_t* __restrict__ dC,
    uint16_t* __restrict__ WB, float* __restrict__ out)
{
    const int tid = threadIdx.x;
    const int g = blockIdx.x;
    if (g < 256) {
        // dC[b][c][j] = bf16( KNORM * data / (invmass * density) )
        int e = g * 256 + tid;             // 4 j each
        int j4 = e & 511, bc = e >> 9;
        int b = bc >> 6;
        float4 dv = *(const float4*)(data + bc * 2048 + j4 * 4);
        float4 de = *(const float4*)(density + b * 2048 + j4 * 4);
        int jb = (b * 2048 + j4 * 4) * 3 + 2;
        float m0 = locs[jb], m1 = locs[jb + 3], m2 = locs[jb + 6], m3 = locs[jb + 9];
        float v0 = KNORM * dv.x / (m0 * de.x);
        float v1 = KNORM * dv.y / (m1 * de.y);
        float v2 = KNORM * dv.z / (m2 * de.z);
        float v3 = KNORM * dv.w / (m3 * de.w);
        *(uint2*)(dC + bc * 2048 + j4 * 4) = make_uint2(pk2(v0, v1), pk2(v2, v3));
    } else if (g < 272) {
        int jj = (g - 256) * 256 + tid;
        posT[jj] = make_float2(locs[jj * 3], locs[jj * 3 + 1]);
    } else if (g < 272 + NCELL) {
        // WB[cell][ks][ob][lane][jj]: o = ob*16 + (lane&15), c = ks*32 + quad*8 + jj
        int cell = g - 272;
        for (int it = 0; it < 16; it++) {
            int e = it * 256 + tid;
            int ks = e >> 11, ob = (e >> 9) & 3, lane = (e >> 3) & 63, jj = e & 7;
            int o = ob * 16 + (lane & 15);
            int c = ks * 32 + ((lane >> 4) & 3) * 8 + jj;
            union { __hip_bfloat16 h; uint16_t u; } cv;
            cv.h = __float2bfloat16(weight[(o * 64 + c) * 9 + cell]);
            WB[cell * 4096 + e] = cv.u;
        }
    } else {
        // out[b][o][i] = bias[o]  (atomic accumulation target)
        const int gb = g - (272 + NCELL);
#pragma unroll
        for (int r = 0; r < 2; r++) {
            int e4 = (gb * 512 + r * 256 + tid) * 4;
            float bv = bias[(e4 >> 11) & 63];
            *(float4*)(out + e4) = make_float4(bv, bv, bv, bv);
        }
    }
}

// ---------------------------------------------------------------------------
// Fused conv: block = 16-i tile x 512-j quarter, 3 waves = 3 cell-COLUMNS.
// Wave w owns cells {3w, 3w+1, 3w+2} (shared ox -> ru computed once, ox
// folded into pI.x, no per-cell selects). acc[3][4] = 48 VGPR, no spill.
// Only dx/dy duplicated across waves. No LDS staging / no barriers in the
// K-loop; B-frags direct from L2-hot dC. GEMM2 per-wave, 1 barrier,
// 3-slice reduce, fp32 atomics into bias-initialized out.
// ---------------------------------------------------------------------------
__global__ __launch_bounds__(192, 3) void conv_kernel(
    const float2* __restrict__ posT, const uint16_t* __restrict__ dC,
    const uint16_t* __restrict__ WB, float* __restrict__ out)
{
    __shared__ float sft[3][16 * 68];

    const int tid  = threadIdx.x;
    const int lane = tid & 63;
    const int wid  = tid >> 6;                // 0..2 = ox column
    const int cl   = lane & 15;
    const int quad = lane >> 4;
    const int bx   = blockIdx.x;
    const int b    = bx >> 9;
    const int i0   = ((bx >> 2) & 127) * 16;
    const int jb0  = (bx & 3) * 512;          // j-quarter base

    const float2 pI = posT[b * 2048 + i0 + cl];
    const float pix = pI.x + (float)(wid - 1) * 0.05f;   // ox folded in
    const float piy = pI.y;

    f32x4 acc[3][4];
#pragma unroll
    for (int m = 0; m < 3; m++)
#pragma unroll
        for (int nb = 0; nb < 4; nb++) acc[m][nb] = (f32x4){0.f, 0.f, 0.f, 0.f};

    // B-frag base: element (c = nb*16 + cl, j = jb0 + t*32 + quad*8 + jj)
    const uint16_t* rb = dC + (b * 64 + cl) * 2048 + jb0 + quad * 8;
    const float2*  pjb = posT + b * 2048 + jb0 + quad * 8;

#pragma unroll 2
    for (int t = 0; t < 16; t++) {
        B8 bfc[4];
        bfc[0].u = *(const uint4*)(rb +  0 * 2048 + t * 32);
        bfc[1].u = *(const uint4*)(rb + 16 * 2048 + t * 32);
        bfc[2].u = *(const uint4*)(rb + 32 * 2048 + t * 32);
        bfc[3].u = *(const uint4*)(rb + 48 * 2048 + t * 32);

        const float4* pp = (const float4*)(pjb + t * 32);
        float4 q0 = pp[0], q1 = pp[1], q2 = pp[2], q3 = pp[3];

        float axv[8], dyv[8];
        axv[0] = pix - q0.x; dyv[0] = piy - q0.y;
        axv[1] = pix - q0.z; dyv[1] = piy - q0.w;
        axv[2] = pix - q1.x; dyv[2] = piy - q1.y;
        axv[3] = pix - q1.z; dyv[3] = piy - q1.w;
        axv[4] = pix - q2.x; dyv[4] = piy - q2.y;
        axv[5] = pix - q2.z; dyv[5] = piy - q2.w;
        axv[6] = pix - q3.x; dyv[6] = piy - q3.y;
        axv[7] = pix - q3.z; dyv[7] = piy - q3.w;

        // column cells: m=0 oy=-0.05, m=1 oy=0, m=2 oy=+0.05
        // t_m = s - 2*oy*dy - oy^2, s = R2 - ax^2 - dy^2
        float w0[8], w1[8], w2[8];
#pragma unroll
        for (int p = 0; p < 8; p++) {
            float ru = fmaf(-axv[p], axv[p], R2);
            float s  = fmaf(-dyv[p], dyv[p], ru);
            float sp = s - 0.0025f;
            float tm = fmaf( 0.1f, dyv[p], sp);
            float tp = fmaf(-0.1f, dyv[p], sp);
            float m0 = fmaxf(tm, 0.0f);
            float m1 = fmaxf(s,  0.0f);
            float m2 = fmaxf(tp, 0.0f);
            w0[p] = (m0 * m0) * m0;     // knorm folded into dC
            w1[p] = (m1 * m1) * m1;
            w2[p] = (m2 * m2) * m2;
        }

        B8 a0, a1, a2;
        a0.u = make_uint4(pk2(w0[0], w0[1]), pk2(w0[2], w0[3]),
                          pk2(w0[4], w0[5]), pk2(w0[6], w0[7]));
        a1.u = make_uint4(pk2(w1[0], w1[1]), pk2(w1[2], w1[3]),
                          pk2(w1[4], w1[5]), pk2(w1[6], w1[7]));
        a2.u = make_uint4(pk2(w2[0], w2[1]), pk2(w2[2], w2[3]),
                          pk2(w2[4], w2[5]), pk2(w2[6], w2[7]));

#pragma unroll
        for (int nb = 0; nb < 4; nb++) {
            acc[0][nb] = __builtin_amdgcn_mfma_f32_16x16x32_bf16(
                a0.v, bfc[nb].v, acc[0][nb], 0, 0, 0);
            acc[1][nb] = __builtin_amdgcn_mfma_f32_16x16x32_bf16(
                a1.v, bfc[nb].v, acc[1][nb], 0, 0, 0);
            acc[2][nb] = __builtin_amdgcn_mfma_f32_16x16x32_bf16(
                a2.v, bfc[nb].v, acc[2][nb], 0, 0, 0);
        }
    }

    // ---- GEMM2 per wave: 16i x 64o partial over its 3 cells ----------------
    float* scr = &sft[wid][0];
    f32x4 acc2[4];
#pragma unroll
    for (int ob = 0; ob < 4; ob++) acc2[ob] = (f32x4){0.f, 0.f, 0.f, 0.f};

#pragma unroll
    for (int m = 0; m < 3; m++) {
        // C-frag (row=i=quad*4+r, col=c=nb*16+cl) -> scr[i][c]
#pragma unroll
        for (int nb = 0; nb < 4; nb++)
#pragma unroll
            for (int r = 0; r < 4; r++)
                scr[(quad * 4 + r) * 68 + nb * 16 + cl] = acc[m][nb][r];
        // A-frags (m=i=cl, k'=c=quad*8+jj); in-wave LDS ordering via lgkmcnt
        int k = wid * 3 + m;
#pragma unroll
        for (int ks = 0; ks < 2; ks++) {
            const float* fp = &scr[cl * 68 + ks * 32 + quad * 8];
            float4 lo = *(const float4*)fp;
            float4 hi = *(const float4*)(fp + 4);
            B8 af;
            af.u = make_uint4(pk2(lo.x, lo.y), pk2(lo.z, lo.w),
                              pk2(hi.x, hi.y), pk2(hi.z, hi.w));
#pragma unroll
            for (int ob = 0; ob < 4; ob++) {
                B8 wf;
                wf.u = *(const uint4*)(WB + k * 4096 + (ks * 4 + ob) * 512 + lane * 8);
                acc2[ob] = __builtin_amdgcn_mfma_f32_16x16x32_bf16(
                    af.v, wf.v, acc2[ob], 0, 0, 0);
            }
        }
    }

    // acc2 C-frag (row=i=quad*4+r, col o = ob*16+cl) -> scr[i][o]
#pragma unroll
    for (int ob = 0; ob < 4; ob++)
#pragma unroll
        for (int r = 0; r < 4; r++)
            scr[(quad * 4 + r) * 68 + ob * 16 + cl] = acc2[ob][r];
    __syncthreads();

    // reduce the 3 wave slices; fp32 atomics (4-way j-quarter contention)
    for (int e = tid; e < 256; e += 192) {
        int i  = e >> 4;
        int og = e & 15;
        float4 s0 = *(const float4*)&sft[0][i * 68 + og * 4];
        float4 s1 = *(const float4*)&sft[1][i * 68 + og * 4];
        float4 s2 = *(const float4*)&sft[2][i * 68 + og * 4];
        float v0 = s0.x + s1.x + s2.x;
        float v1 = s0.y + s1.y + s2.y;
        float v2 = s0.z + s1.z + s2.z;
        float v3 = s0.w + s1.w + s2.w;
        float* op = out + (b * 64 + og * 4) * 2048 + i0 + i;
        unsafeAtomicAdd(op + 0 * 2048, v0);
        unsafeAtomicAdd(op + 1 * 2048, v1);
        unsafeAtomicAdd(op + 2 * 2048, v2);
        unsafeAtomicAdd(op + 3 * 2048, v3);
    }
}

extern "C" void kernel_launch(void* const* d_in, const int* in_sizes, int n_in,
                              void* d_out, int out_size, void* d_ws, size_t ws_size,
                              hipStream_t stream)
{
    const float* locs    = (const float*)d_in[0];   // (B, N, 3)
    const float* data    = (const float*)d_in[1];   // (B, CIN, N)
    const float* density = (const float*)d_in[2];   // (B, N)
    const float* weight  = (const float*)d_in[3];   // (COUT, CIN, 9)
    const float* bias    = (const float*)d_in[4];   // (COUT,)
    float* out = (float*)d_out;                     // (B, COUT, N)

    float2*   posT = (float2*)d_ws;                             // 32768 B
    uint16_t* dC   = (uint16_t*)((char*)d_ws + 32768);          // 524288 B
    uint16_t* WB   = (uint16_t*)((char*)d_ws + 32768 + 524288); // 73728 B

    prep_kernel<<<272 + NCELL + 128, 256, 0, stream>>>(
        locs, data, density, weight, bias, posT, dC, WB, out);
    conv_kernel<<<BATCH * 128 * 4, 192, 0, stream>>>(posT, dC, WB, out);
}

// Round 10
// 101.398 us; speedup vs baseline: 1.1106x; 1.0737x over previous
//
#include <hip/hip_runtime.h>
#include <hip/hip_bf16.h>
#include <stdint.h>

#define BATCH 2
#define NPTS  2048
#define CIN   64
#define COUT  64
#define NCELL 9

// knorm = 315 / (64*pi*0.1^9) -- folded into dC at prep
#define KNORM 1.5666851e9f
#define R2 0.01f

typedef __attribute__((ext_vector_type(8))) __bf16 bf16x8;
typedef __attribute__((ext_vector_type(4))) float  f32x4;

union B8 { uint4 u; bf16x8 v; };

static __device__ __forceinline__ unsigned pk2(float a, float b) {
    union { __hip_bfloat162 h; unsigned u; } cv;
    cv.h = __float22bfloat162_rn(make_float2(a, b));
    return cv.u;
}

// ---------------------------------------------------------------------------
// Workspace:
//   posT  float2[B*N]                       32 KB
//   dC    bf16  [B][C][N]  (c-major)       512 KB  (L2-resident; KNORM folded)
//   WB    bf16  [9][2ks][4ob][64][8]        72 KB  (GEMM2 B pre-swizzled frags)
//   part  fp32  [8jq][B][128it][16i][64o]    8 MB  (j-split partials)
// ---------------------------------------------------------------------------

__global__ __launch_bounds__(256) void prep_kernel(
    const float* __restrict__ locs, const float* __restrict__ data,
    const float* __restrict__ density, const float* __restrict__ weight,
    float2* __restrict__ posT, uint16_t* __restrict__ dC,
    uint16_t* __restrict__ WB)
{
    const int tid = threadIdx.x;
    const int g = blockIdx.x;
    if (g < 256) {
        // dC[b][c][j] = bf16( KNORM * data / (invmass * density) )
        int e = g * 256 + tid;             // 4 j each
        int j4 = e & 511, bc = e >> 9;
        int b = bc >> 6;
        float4 dv = *(const float4*)(data + bc * 2048 + j4 * 4);
        float4 de = *(const float4*)(density + b * 2048 + j4 * 4);
        int jb = (b * 2048 + j4 * 4) * 3 + 2;
        float m0 = locs[jb], m1 = locs[jb + 3], m2 = locs[jb + 6], m3 = locs[jb + 9];
        float v0 = KNORM * dv.x / (m0 * de.x);
        float v1 = KNORM * dv.y / (m1 * de.y);
        float v2 = KNORM * dv.z / (m2 * de.z);
        float v3 = KNORM * dv.w / (m3 * de.w);
        *(uint2*)(dC + bc * 2048 + j4 * 4) = make_uint2(pk2(v0, v1), pk2(v2, v3));
    } else if (g < 272) {
        int jj = (g - 256) * 256 + tid;
        posT[jj] = make_float2(locs[jj * 3], locs[jj * 3 + 1]);
    } else {
        // WB[cell][ks][ob][lane][jj]: o = ob*16 + (lane&15), c = ks*32 + quad*8 + jj
        int cell = g - 272;
        for (int it = 0; it < 16; it++) {
            int e = it * 256 + tid;
            int ks = e >> 11, ob = (e >> 9) & 3, lane = (e >> 3) & 63, jj = e & 7;
            int o = ob * 16 + (lane & 15);
            int c = ks * 32 + ((lane >> 4) & 3) * 8 + jj;
            union { __hip_bfloat16 h; uint16_t u; } cv;
            cv.h = __float2bfloat16(weight[(o * 64 + c) * 9 + cell]);
            WB[cell * 4096 + e] = cv.u;
        }
    }
}

// ---------------------------------------------------------------------------
// Fused conv: block = 16-i tile x 256-j eighth (8 chunks of 32 j), 3 waves =
// 3 cell-columns (shared ox folded into pI.x; no selects). Block's pos slab
// cached in LDS up-front (quad-broadcast ds_reads in the loop). dC B-frags
// direct from L2 with explicit 1-deep register prefetch. GEMM2 per-wave,
// 1 barrier, 3-slice reduce, plain float4 partial stores (no atomics).
// ---------------------------------------------------------------------------
__global__ __launch_bounds__(192, 4) void conv_kernel(
    const float2* __restrict__ posT, const uint16_t* __restrict__ dC,
    const uint16_t* __restrict__ WB, float* __restrict__ part)
{
    __shared__ float4 pjs[128];               // 256 j-positions (float2 pairs)
    __shared__ float  sft[3][16 * 68];

    const int tid  = threadIdx.x;
    const int lane = tid & 63;
    const int wid  = tid >> 6;                // 0..2 = ox column
    const int cl   = lane & 15;
    const int quad = lane >> 4;
    const int bx   = blockIdx.x;
    const int b    = bx >> 10;
    const int it   = (bx >> 3) & 127;
    const int i0   = it * 16;
    const int jq   = bx & 7;
    const int jb0  = jq * 256;                // j-eighth base

    // cooperative pos-slab load (256 float2 = 128 float4)
    if (tid < 128)
        pjs[tid] = ((const float4*)(posT + b * 2048 + jb0))[tid];

    const float2 pI = posT[b * 2048 + i0 + cl];
    const float pix = pI.x + (float)(wid - 1) * 0.05f;   // ox folded in
    const float piy = pI.y;

    f32x4 acc[3][4];
#pragma unroll
    for (int m = 0; m < 3; m++)
#pragma unroll
        for (int nb = 0; nb < 4; nb++) acc[m][nb] = (f32x4){0.f, 0.f, 0.f, 0.f};

    // B-frag base: element (c = nb*16 + cl, j = jb0 + t*32 + quad*8 + jj)
    const uint16_t* rb = dC + (b * 64 + cl) * 2048 + jb0 + quad * 8;

    B8 bfc[4];
    bfc[0].u = *(const uint4*)(rb +  0 * 2048);
    bfc[1].u = *(const uint4*)(rb + 16 * 2048);
    bfc[2].u = *(const uint4*)(rb + 32 * 2048);
    bfc[3].u = *(const uint4*)(rb + 48 * 2048);

    __syncthreads();                          // pjs ready

    for (int t = 0; t < 8; t++) {
        B8 bfn[4];
        if (t < 7) {                          // 1-deep prefetch of next chunk
            bfn[0].u = *(const uint4*)(rb +  0 * 2048 + (t + 1) * 32);
            bfn[1].u = *(const uint4*)(rb + 16 * 2048 + (t + 1) * 32);
            bfn[2].u = *(const uint4*)(rb + 32 * 2048 + (t + 1) * 32);
            bfn[3].u = *(const uint4*)(rb + 48 * 2048 + (t + 1) * 32);
        }

        // my 8 pair geometries; pos via quad-broadcast LDS reads
        const float4* pp = &pjs[t * 16 + quad * 4];
        float4 q0 = pp[0], q1 = pp[1], q2 = pp[2], q3 = pp[3];

        float w0a, w1a, w2a;                  // previous-p w values
        uint32_t a0u[4], a1u[4], a2u[4];
#define GEOM(p, QX, QY)                                                        \
        {                                                                      \
            float ax = pix - (QX);                                             \
            float dy = piy - (QY);                                             \
            float ru = fmaf(-ax, ax, R2);                                      \
            float s  = fmaf(-dy, dy, ru);                                      \
            float sp = s - 0.0025f;                                            \
            float tm = fmaf( 0.1f, dy, sp);                                    \
            float tp = fmaf(-0.1f, dy, sp);                                    \
            float m0 = fmaxf(tm, 0.0f);                                        \
            float m1 = fmaxf(s,  0.0f);                                        \
            float m2 = fmaxf(tp, 0.0f);                                        \
            float v0 = (m0 * m0) * m0;                                         \
            float v1 = (m1 * m1) * m1;                                         \
            float v2 = (m2 * m2) * m2;                                         \
            if ((p) & 1) {                                                     \
                a0u[(p) >> 1] = pk2(w0a, v0);                                  \
                a1u[(p) >> 1] = pk2(w1a, v1);                                  \
                a2u[(p) >> 1] = pk2(w2a, v2);                                  \
            } else { w0a = v0; w1a = v1; w2a = v2; }                           \
        }
        GEOM(0, q0.x, q0.y) GEOM(1, q0.z, q0.w)
        GEOM(2, q1.x, q1.y) GEOM(3, q1.z, q1.w)
        GEOM(4, q2.x, q2.y) GEOM(5, q2.z, q2.w)
        GEOM(6, q3.x, q3.y) GEOM(7, q3.z, q3.w)
#undef GEOM

        B8 a0, a1, a2;
        a0.u = make_uint4(a0u[0], a0u[1], a0u[2], a0u[3]);
        a1.u = make_uint4(a1u[0], a1u[1], a1u[2], a1u[3]);
        a2.u = make_uint4(a2u[0], a2u[1], a2u[2], a2u[3]);

#pragma unroll
        for (int nb = 0; nb < 4; nb++) {
            acc[0][nb] = __builtin_amdgcn_mfma_f32_16x16x32_bf16(
                a0.v, bfc[nb].v, acc[0][nb], 0, 0, 0);
            acc[1][nb] = __builtin_amdgcn_mfma_f32_16x16x32_bf16(
                a1.v, bfc[nb].v, acc[1][nb], 0, 0, 0);
            acc[2][nb] = __builtin_amdgcn_mfma_f32_16x16x32_bf16(
                a2.v, bfc[nb].v, acc[2][nb], 0, 0, 0);
        }

        if (t < 7) {
            bfc[0] = bfn[0]; bfc[1] = bfn[1];
            bfc[2] = bfn[2]; bfc[3] = bfn[3];
        }
    }

    // ---- GEMM2 per wave: 16i x 64o partial over its 3 cells ----------------
    float* scr = &sft[wid][0];
    f32x4 acc2[4];
#pragma unroll
    for (int ob = 0; ob < 4; ob++) acc2[ob] = (f32x4){0.f, 0.f, 0.f, 0.f};

#pragma unroll
    for (int m = 0; m < 3; m++) {
        // C-frag (row=i=quad*4+r, col=c=nb*16+cl) -> scr[i][c]
#pragma unroll
        for (int nb = 0; nb < 4; nb++)
#pragma unroll
            for (int r = 0; r < 4; r++)
                scr[(quad * 4 + r) * 68 + nb * 16 + cl] = acc[m][nb][r];
        // A-frags (m=i=cl, k'=c=quad*8+jj); in-wave ordering via lgkmcnt
        int k = wid * 3 + m;
#pragma unroll
        for (int ks = 0; ks < 2; ks++) {
            const float* fp = &scr[cl * 68 + ks * 32 + quad * 8];
            float4 lo = *(const float4*)fp;
            float4 hi = *(const float4*)(fp + 4);
            B8 af;
            af.u = make_uint4(pk2(lo.x, lo.y), pk2(lo.z, lo.w),
                              pk2(hi.x, hi.y), pk2(hi.z, hi.w));
#pragma unroll
            for (int ob = 0; ob < 4; ob++) {
                B8 wf;
                wf.u = *(const uint4*)(WB + k * 4096 + (ks * 4 + ob) * 512 + lane * 8);
                acc2[ob] = __builtin_amdgcn_mfma_f32_16x16x32_bf16(
                    af.v, wf.v, acc2[ob], 0, 0, 0);
            }
        }
    }

    // acc2 C-frag (row=i=quad*4+r, col o = ob*16+cl) -> scr[i][o]
#pragma unroll
    for (int ob = 0; ob < 4; ob++)
#pragma unroll
        for (int r = 0; r < 4; r++)
            scr[(quad * 4 + r) * 68 + ob * 16 + cl] = acc2[ob][r];
    __syncthreads();

    // reduce the 3 wave slices -> part[jq][b][it][i][o] (coalesced float4)
    float* base = part + (((jq * BATCH + b) * 128 + it) << 10);
    for (int e = tid; e < 256; e += 192) {
        int i  = e >> 4;
        int og = e & 15;
        float4 s0 = *(const float4*)&sft[0][i * 68 + og * 4];
        float4 s1 = *(const float4*)&sft[1][i * 68 + og * 4];
        float4 s2 = *(const float4*)&sft[2][i * 68 + og * 4];
        float4 v = make_float4(s0.x + s1.x + s2.x, s0.y + s1.y + s2.y,
                               s0.z + s1.z + s2.z, s0.w + s1.w + s2.w);
        *(float4*)(base + i * 64 + og * 4) = v;
    }
}

// ---------------------------------------------------------------------------
// out[b][o][i] = bias[o] + sum_jq part[jq][b][i>>4][i&15][o]
// thread = (b, it, og, i): stores coalesced in i (16 lanes x 4B per o).
// ---------------------------------------------------------------------------
__global__ __launch_bounds__(256) void reduce_kernel(
    const float* __restrict__ part, const float* __restrict__ bias,
    float* __restrict__ out)
{
    const int e  = blockIdx.x * 256 + threadIdx.x;   // 65536 threads
    const int i  = e & 15;
    const int og = (e >> 4) & 15;
    const int it = (e >> 8) & 127;
    const int b  = e >> 15;

    const float* p = part + (((b * 128 + it) << 10) + i * 64 + og * 4);
    float4 s = *(const float4*)p;
#pragma unroll
    for (int jqq = 1; jqq < 8; jqq++) {
        float4 q = *(const float4*)(p + jqq * (BATCH * 128 * 1024));
        s.x += q.x; s.y += q.y; s.z += q.z; s.w += q.w;
    }
    const float4 bv = *(const float4*)(bias + og * 4);
    float* op = out + ((b * 64 + og * 4) * 2048) + it * 16 + i;
    op[0 * 2048] = s.x + bv.x;
    op[1 * 2048] = s.y + bv.y;
    op[2 * 2048] = s.z + bv.z;
    op[3 * 2048] = s.w + bv.w;
}

extern "C" void kernel_launch(void* const* d_in, const int* in_sizes, int n_in,
                              void* d_out, int out_size, void* d_ws, size_t ws_size,
                              hipStream_t stream)
{
    const float* locs    = (const float*)d_in[0];   // (B, N, 3)
    const float* data    = (const float*)d_in[1];   // (B, CIN, N)
    const float* density = (const float*)d_in[2];   // (B, N)
    const float* weight  = (const float*)d_in[3];   // (COUT, CIN, 9)
    const float* bias    = (const float*)d_in[4];   // (COUT,)
    float* out = (float*)d_out;                     // (B, COUT, N)

    float2*   posT = (float2*)d_ws;                             // 32768 B
    uint16_t* dC   = (uint16_t*)((char*)d_ws + 32768);          // 524288 B
    uint16_t* WB   = (uint16_t*)((char*)d_ws + 32768 + 524288); // 73728 B
    float*    part = (float*)((char*)d_ws + 32768 + 524288 + 73728); // 8 MB

    prep_kernel<<<272 + NCELL, 256, 0, stream>>>(
        locs, data, density, weight, posT, dC, WB);
    conv_kernel<<<BATCH * 128 * 8, 192, 0, stream>>>(posT, dC, WB, part);
    reduce_kernel<<<256, 256, 0, stream>>>(part, bias, out);
}

// Round 11
// 93.200 us; speedup vs baseline: 1.2083x; 1.0880x over previous
//
#include <hip/hip_runtime.h>
#include <hip/hip_bf16.h>
#include <stdint.h>

#define BATCH 2
#define NPTS  2048
#define CIN   64
#define COUT  64
#define NCELL 9

// knorm = 315 / (64*pi*0.1^9) -- folded into dC at prep
#define KNORM 1.5666851e9f
#define R2 0.01f

typedef __attribute__((ext_vector_type(8))) __bf16 bf16x8;
typedef __attribute__((ext_vector_type(4))) float  f32x4;

union B8 { uint4 u; bf16x8 v; };

static __device__ __forceinline__ unsigned pk2(float a, float b) {
    union { __hip_bfloat162 h; unsigned u; } cv;
    cv.h = __float22bfloat162_rn(make_float2(a, b));
    return cv.u;
}

// ---------------------------------------------------------------------------
// Workspace:
//   posT  float2[B*N]                       32 KB
//   dC    bf16  [B][jt=64][c=64][jl=32]    512 KB  TILE-SWIZZLED: each 64c x
//         32j chunk is a contiguous 4 KB tile (B-frag loads lane-contiguous,
//         L1-set-friendly; the [b][c][j] layout aliased all rows to one set)
//   WB    bf16  [9][2ks][4ob][64][8]        72 KB  (GEMM2 B pre-swizzled frags)
//   part  fp32  [8jq][B][128it][16i][64o]    8 MB  (j-split partials)
// ---------------------------------------------------------------------------

__global__ __launch_bounds__(256) void prep_kernel(
    const float* __restrict__ locs, const float* __restrict__ data,
    const float* __restrict__ density, const float* __restrict__ weight,
    float2* __restrict__ posT, uint16_t* __restrict__ dC,
    uint16_t* __restrict__ WB)
{
    const int tid = threadIdx.x;
    const int g = blockIdx.x;
    if (g < 256) {
        // dC[b][jt][c][jl] = bf16( KNORM * data / (invmass * density) )
        int e = g * 256 + tid;             // 4 j each
        int j4 = e & 511, bc = e >> 9;
        int b = bc >> 6, c = bc & 63;
        float4 dv = *(const float4*)(data + bc * 2048 + j4 * 4);
        float4 de = *(const float4*)(density + b * 2048 + j4 * 4);
        int jb = (b * 2048 + j4 * 4) * 3 + 2;
        float m0 = locs[jb], m1 = locs[jb + 3], m2 = locs[jb + 6], m3 = locs[jb + 9];
        float v0 = KNORM * dv.x / (m0 * de.x);
        float v1 = KNORM * dv.y / (m1 * de.y);
        float v2 = KNORM * dv.z / (m2 * de.z);
        float v3 = KNORM * dv.w / (m3 * de.w);
        int jt = j4 >> 3, jl = (j4 & 7) * 4;
        int idx = ((b * 64 + jt) * 64 + c) * 32 + jl;
        *(uint2*)(dC + idx) = make_uint2(pk2(v0, v1), pk2(v2, v3));
    } else if (g < 272) {
        int jj = (g - 256) * 256 + tid;
        posT[jj] = make_float2(locs[jj * 3], locs[jj * 3 + 1]);
    } else {
        // WB[cell][ks][ob][lane][jj]: o = ob*16 + (lane&15), c = ks*32 + quad*8 + jj
        int cell = g - 272;
        for (int it = 0; it < 16; it++) {
            int e = it * 256 + tid;
            int ks = e >> 11, ob = (e >> 9) & 3, lane = (e >> 3) & 63, jj = e & 7;
            int o = ob * 16 + (lane & 15);
            int c = ks * 32 + ((lane >> 4) & 3) * 8 + jj;
            union { __hip_bfloat16 h; uint16_t u; } cv;
            cv.h = __float2bfloat16(weight[(o * 64 + c) * 9 + cell]);
            WB[cell * 4096 + e] = cv.u;
        }
    }
}

// ---------------------------------------------------------------------------
// Fused conv: block = 16-i tile x 256-j eighth (8 chunks of 32 j), 3 waves =
// 3 cell-columns (shared ox folded into pI.x). pos slab in LDS. dC B-frags
// from contiguous 4 KB tiles (1 KB lane-contiguous per load) with 1-deep
// register prefetch. GEMM2 per-wave, 1 barrier, 3-slice reduce, float4
// partial stores (no atomics).
// ---------------------------------------------------------------------------
__global__ __launch_bounds__(192, 5) void conv_kernel(
    const float2* __restrict__ posT, const uint16_t* __restrict__ dC,
    const uint16_t* __restrict__ WB, float* __restrict__ part)
{
    __shared__ float4 pjs[128];               // 256 j-positions (float2 pairs)
    __shared__ float  sft[3][16 * 68];

    const int tid  = threadIdx.x;
    const int lane = tid & 63;
    const int wid  = tid >> 6;                // 0..2 = ox column
    const int cl   = lane & 15;
    const int quad = lane >> 4;
    const int bx   = blockIdx.x;
    const int b    = bx >> 10;
    const int it   = (bx >> 3) & 127;
    const int i0   = it * 16;
    const int jq   = bx & 7;
    const int jb0  = jq * 256;                // j-eighth base

    // cooperative pos-slab load (256 float2 = 128 float4)
    if (tid < 128)
        pjs[tid] = ((const float4*)(posT + b * 2048 + jb0))[tid];

    const float2 pI = posT[b * 2048 + i0 + cl];
    const float pix = pI.x + (float)(wid - 1) * 0.05f;   // ox folded in
    const float piy = pI.y;

    f32x4 acc[3][4];
#pragma unroll
    for (int m = 0; m < 3; m++)
#pragma unroll
        for (int nb = 0; nb < 4; nb++) acc[m][nb] = (f32x4){0.f, 0.f, 0.f, 0.f};

    // B-frag: tile t at dC + (b*64 + jq*8 + t)*2048; within tile, lane reads
    // (c = nb*16 + cl) * 32 + quad*8  -> 1 KB contiguous per wave-load.
    const uint16_t* rb = dC + (b * 64 + jq * 8) * 2048 + cl * 32 + quad * 8;

    B8 bfc[4];
    bfc[0].u = *(const uint4*)(rb +  0 * 512);
    bfc[1].u = *(const uint4*)(rb +  1 * 512);
    bfc[2].u = *(const uint4*)(rb +  2 * 512);
    bfc[3].u = *(const uint4*)(rb +  3 * 512);

    __syncthreads();                          // pjs ready

    for (int t = 0; t < 8; t++) {
        B8 bfn[4];
        if (t < 7) {                          // 1-deep prefetch of next tile
            const uint16_t* rn = rb + (t + 1) * 2048;
            bfn[0].u = *(const uint4*)(rn +  0 * 512);
            bfn[1].u = *(const uint4*)(rn +  1 * 512);
            bfn[2].u = *(const uint4*)(rn +  2 * 512);
            bfn[3].u = *(const uint4*)(rn +  3 * 512);
        }

        // my 8 pair geometries; pos via quad-broadcast LDS reads
        const float4* pp = &pjs[t * 16 + quad * 4];
        float4 q0 = pp[0], q1 = pp[1], q2 = pp[2], q3 = pp[3];

        float w0a, w1a, w2a;                  // previous-p w values
        uint32_t a0u[4], a1u[4], a2u[4];
#define GEOM(p, QX, QY)                                                        \
        {                                                                      \
            float ax = pix - (QX);                                             \
            float dy = piy - (QY);                                             \
            float ru = fmaf(-ax, ax, R2);                                      \
            float s  = fmaf(-dy, dy, ru);                                      \
            float sp = s - 0.0025f;                                            \
            float tm = fmaf( 0.1f, dy, sp);                                    \
            float tp = fmaf(-0.1f, dy, sp);                                    \
            float m0 = fmaxf(tm, 0.0f);                                        \
            float m1 = fmaxf(s,  0.0f);                                        \
            float m2 = fmaxf(tp, 0.0f);                                        \
            float v0 = (m0 * m0) * m0;                                         \
            float v1 = (m1 * m1) * m1;                                         \
            float v2 = (m2 * m2) * m2;                                         \
            if ((p) & 1) {                                                     \
                a0u[(p) >> 1] = pk2(w0a, v0);                                  \
                a1u[(p) >> 1] = pk2(w1a, v1);                                  \
                a2u[(p) >> 1] = pk2(w2a, v2);                                  \
            } else { w0a = v0; w1a = v1; w2a = v2; }                           \
        }
        GEOM(0, q0.x, q0.y) GEOM(1, q0.z, q0.w)
        GEOM(2, q1.x, q1.y) GEOM(3, q1.z, q1.w)
        GEOM(4, q2.x, q2.y) GEOM(5, q2.z, q2.w)
        GEOM(6, q3.x, q3.y) GEOM(7, q3.z, q3.w)
#undef GEOM

        B8 a0, a1, a2;
        a0.u = make_uint4(a0u[0], a0u[1], a0u[2], a0u[3]);
        a1.u = make_uint4(a1u[0], a1u[1], a1u[2], a1u[3]);
        a2.u = make_uint4(a2u[0], a2u[1], a2u[2], a2u[3]);

#pragma unroll
        for (int nb = 0; nb < 4; nb++) {
            acc[0][nb] = __builtin_amdgcn_mfma_f32_16x16x32_bf16(
                a0.v, bfc[nb].v, acc[0][nb], 0, 0, 0);
            acc[1][nb] = __builtin_amdgcn_mfma_f32_16x16x32_bf16(
                a1.v, bfc[nb].v, acc[1][nb], 0, 0, 0);
            acc[2][nb] = __builtin_amdgcn_mfma_f32_16x16x32_bf16(
                a2.v, bfc[nb].v, acc[2][nb], 0, 0, 0);
        }

        if (t < 7) {
            bfc[0] = bfn[0]; bfc[1] = bfn[1];
            bfc[2] = bfn[2]; bfc[3] = bfn[3];
        }
    }

    // ---- GEMM2 per wave: 16i x 64o partial over its 3 cells ----------------
    float* scr = &sft[wid][0];
    f32x4 acc2[4];
#pragma unroll
    for (int ob = 0; ob < 4; ob++) acc2[ob] = (f32x4){0.f, 0.f, 0.f, 0.f};

#pragma unroll
    for (int m = 0; m < 3; m++) {
        // C-frag (row=i=quad*4+r, col=c=nb*16+cl) -> scr[i][c]
#pragma unroll
        for (int nb = 0; nb < 4; nb++)
#pragma unroll
            for (int r = 0; r < 4; r++)
                scr[(quad * 4 + r) * 68 + nb * 16 + cl] = acc[m][nb][r];
        // A-frags (m=i=cl, k'=c=quad*8+jj); in-wave ordering via lgkmcnt
        int k = wid * 3 + m;
#pragma unroll
        for (int ks = 0; ks < 2; ks++) {
            const float* fp = &scr[cl * 68 + ks * 32 + quad * 8];
            float4 lo = *(const float4*)fp;
            float4 hi = *(const float4*)(fp + 4);
            B8 af;
            af.u = make_uint4(pk2(lo.x, lo.y), pk2(lo.z, lo.w),
                              pk2(hi.x, hi.y), pk2(hi.z, hi.w));
#pragma unroll
            for (int ob = 0; ob < 4; ob++) {
                B8 wf;
                wf.u = *(const uint4*)(WB + k * 4096 + (ks * 4 + ob) * 512 + lane * 8);
                acc2[ob] = __builtin_amdgcn_mfma_f32_16x16x32_bf16(
                    af.v, wf.v, acc2[ob], 0, 0, 0);
            }
        }
    }

    // acc2 C-frag (row=i=quad*4+r, col o = ob*16+cl) -> scr[i][o]
#pragma unroll
    for (int ob = 0; ob < 4; ob++)
#pragma unroll
        for (int r = 0; r < 4; r++)
            scr[(quad * 4 + r) * 68 + ob * 16 + cl] = acc2[ob][r];
    __syncthreads();

    // reduce the 3 wave slices -> part[jq][b][it][i][o] (coalesced float4)
    float* base = part + (((jq * BATCH + b) * 128 + it) << 10);
    for (int e = tid; e < 256; e += 192) {
        int i  = e >> 4;
        int og = e & 15;
        float4 s0 = *(const float4*)&sft[0][i * 68 + og * 4];
        float4 s1 = *(const float4*)&sft[1][i * 68 + og * 4];
        float4 s2 = *(const float4*)&sft[2][i * 68 + og * 4];
        float4 v = make_float4(s0.x + s1.x + s2.x, s0.y + s1.y + s2.y,
                               s0.z + s1.z + s2.z, s0.w + s1.w + s2.w);
        *(float4*)(base + i * 64 + og * 4) = v;
    }
}

// ---------------------------------------------------------------------------
// out[b][o][i] = bias[o] + sum_jq part[jq][b][i>>4][i&15][o]
// ---------------------------------------------------------------------------
__global__ __launch_bounds__(256) void reduce_kernel(
    const float* __restrict__ part, const float* __restrict__ bias,
    float* __restrict__ out)
{
    const int e  = blockIdx.x * 256 + threadIdx.x;   // 65536 threads
    const int i  = e & 15;
    const int og = (e >> 4) & 15;
    const int it = (e >> 8) & 127;
    const int b  = e >> 15;

    const float* p = part + (((b * 128 + it) << 10) + i * 64 + og * 4);
    float4 s = *(const float4*)p;
#pragma unroll
    for (int jqq = 1; jqq < 8; jqq++) {
        float4 q = *(const float4*)(p + jqq * (BATCH * 128 * 1024));
        s.x += q.x; s.y += q.y; s.z += q.z; s.w += q.w;
    }
    const float4 bv = *(const float4*)(bias + og * 4);
    float* op = out + ((b * 64 + og * 4) * 2048) + it * 16 + i;
    op[0 * 2048] = s.x + bv.x;
    op[1 * 2048] = s.y + bv.y;
    op[2 * 2048] = s.z + bv.z;
    op[3 * 2048] = s.w + bv.w;
}

extern "C" void kernel_launch(void* const* d_in, const int* in_sizes, int n_in,
                              void* d_out, int out_size, void* d_ws, size_t ws_size,
                              hipStream_t stream)
{
    const float* locs    = (const float*)d_in[0];   // (B, N, 3)
    const float* data    = (const float*)d_in[1];   // (B, CIN, N)
    const float* density = (const float*)d_in[2];   // (B, N)
    const float* weight  = (const float*)d_in[3];   // (COUT, CIN, 9)
    const float* bias    = (const float*)d_in[4];   // (COUT,)
    float* out = (float*)d_out;                     // (B, COUT, N)

    float2*   posT = (float2*)d_ws;                             // 32768 B
    uint16_t* dC   = (uint16_t*)((char*)d_ws + 32768);          // 524288 B
    uint16_t* WB   = (uint16_t*)((char*)d_ws + 32768 + 524288); // 73728 B
    float*    part = (float*)((char*)d_ws + 32768 + 524288 + 73728); // 8 MB

    prep_kernel<<<272 + NCELL, 256, 0, stream>>>(
        locs, data, density, weight, posT, dC, WB);
    conv_kernel<<<BATCH * 128 * 8, 192, 0, stream>>>(posT, dC, WB, part);
    reduce_kernel<<<256, 256, 0, stream>>>(part, bias, out);
}